// Round 1
// baseline (6224.454 us; speedup 1.0000x reference)
//
#include <hip/hip_runtime.h>
#include <cstdint>
#include <cstddef>

// Problem constants (from reference)
constexpr int N = 50000;   // nodes
constexpr int D = 256;     // D_IN == D_OUT
constexpr int E = 400000;  // edges per relation
constexpr int R = 4;       // relations

// ---------------------------------------------------------------------------
// Scatter: one wave per edge iteration. 64 lanes each move 4 consecutive
// floats of the 256-float source row into msg[dst] via native f32 atomics.
// Lane 0 bumps the (float) degree counter.
// ---------------------------------------------------------------------------
__global__ __launch_bounds__(256)
void scatter_kernel(const float* __restrict__ x,
                    const int* __restrict__ src,
                    const int* __restrict__ dst,
                    float* __restrict__ msg,
                    float* __restrict__ deg) {
    const int wave   = (blockIdx.x * blockDim.x + threadIdx.x) >> 6;
    const int lane   = threadIdx.x & 63;
    const int nwaves = (gridDim.x * blockDim.x) >> 6;
    for (int e = wave; e < E; e += nwaves) {
        const int s = src[e];
        const int d = dst[e];
        if (lane == 0) unsafeAtomicAdd(&deg[d], 1.0f);
        const float4 v =
            *reinterpret_cast<const float4*>(x + (size_t)s * D + lane * 4);
        float* p = msg + (size_t)d * D + lane * 4;
        unsafeAtomicAdd(p + 0, v.x);
        unsafeAtomicAdd(p + 1, v.y);
        unsafeAtomicAdd(p + 2, v.z);
        unsafeAtomicAdd(p + 3, v.w);
    }
}

// deg -> 1/max(deg,1)   (DGL clamps zero in-degree to 1)
__global__ void rdeg_kernel(float* __restrict__ deg) {
    const int i = blockIdx.x * blockDim.x + threadIdx.x;
    if (i < N) deg[i] = 1.0f / fmaxf(deg[i], 1.0f);
}

// ---------------------------------------------------------------------------
// Tiled fp32 GEMM: C[M,256] (+)= (A * rowscale) @ W, W is [256,256].
// BM=BN=64, BK=16, 256 threads, 4x4 micro-tile per thread.
// INIT: C = acc + bias[col]   else: C += acc
// ---------------------------------------------------------------------------
template <bool INIT>
__global__ __launch_bounds__(256)
void gemm64(const float* __restrict__ A, const float* __restrict__ W,
            const float* __restrict__ rowscale, const float* __restrict__ bias,
            float* __restrict__ C) {
    __shared__ float As[16][65];  // [k][m] transposed, +1 pad
    __shared__ float Bs[16][65];  // [k][n], +1 pad

    const int t  = threadIdx.x;
    const int m0 = blockIdx.x * 64;
    const int n0 = blockIdx.y * 64;
    const int tx = t & 15;    // output col group
    const int ty = t >> 4;    // output row group

    // A tile load mapping: 64 rows x 16 k, float4 per thread
    const int ar   = t >> 2;        // 0..63
    const int ac   = (t & 3) * 4;   // 0,4,8,12
    const int arow = m0 + ar;
    const bool arow_ok = (arow < N);
    const float rs = arow_ok ? (rowscale ? rowscale[arow] : 1.0f) : 0.0f;

    // W tile load mapping: 16 k x 64 cols, float4 per thread
    const int br = t >> 4;          // 0..15
    const int bc = (t & 15) * 4;    // 0..60

    float acc[4][4] = {};

    for (int k0 = 0; k0 < D; k0 += 16) {
        float4 av = make_float4(0.f, 0.f, 0.f, 0.f);
        if (arow_ok)
            av = *reinterpret_cast<const float4*>(A + (size_t)arow * D + k0 + ac);
        const float4 bv =
            *reinterpret_cast<const float4*>(W + (size_t)(k0 + br) * D + n0 + bc);

        __syncthreads();  // previous iteration's reads done
        As[ac + 0][ar] = av.x * rs;
        As[ac + 1][ar] = av.y * rs;
        As[ac + 2][ar] = av.z * rs;
        As[ac + 3][ar] = av.w * rs;
        Bs[br][bc + 0] = bv.x;
        Bs[br][bc + 1] = bv.y;
        Bs[br][bc + 2] = bv.z;
        Bs[br][bc + 3] = bv.w;
        __syncthreads();

#pragma unroll
        for (int k = 0; k < 16; ++k) {
            float a[4], b[4];
#pragma unroll
            for (int i = 0; i < 4; ++i) a[i] = As[k][ty * 4 + i];
#pragma unroll
            for (int j = 0; j < 4; ++j) b[j] = Bs[k][tx * 4 + j];
#pragma unroll
            for (int i = 0; i < 4; ++i)
#pragma unroll
                for (int j = 0; j < 4; ++j) acc[i][j] += a[i] * b[j];
        }
    }

#pragma unroll
    for (int i = 0; i < 4; ++i) {
        const int row = m0 + ty * 4 + i;
        if (row >= N) continue;
#pragma unroll
        for (int j = 0; j < 4; ++j) {
            const int col = n0 + tx * 4 + j;
            const size_t idx = (size_t)row * D + col;
            if (INIT)
                C[idx] = acc[i][j] + bias[col];
            else
                C[idx] += acc[i][j];
        }
    }
}

__global__ void tanh_kernel(float* __restrict__ out, int n4) {
    int i = blockIdx.x * blockDim.x + threadIdx.x;
    const int stride = gridDim.x * blockDim.x;
    float4* p = reinterpret_cast<float4*>(out);
    for (; i < n4; i += stride) {
        float4 v = p[i];
        v.x = tanhf(v.x);
        v.y = tanhf(v.y);
        v.z = tanhf(v.z);
        v.w = tanhf(v.w);
        p[i] = v;
    }
}

extern "C" void kernel_launch(void* const* d_in, const int* in_sizes, int n_in,
                              void* d_out, int out_size, void* d_ws, size_t ws_size,
                              hipStream_t stream) {
    const float* x           = (const float*)d_in[0];
    const int*   edges       = (const int*)d_in[1];   // [4][2][400000] int32
    const float* weight      = (const float*)d_in[2]; // [4][256][256]
    const float* loop_weight = (const float*)d_in[3]; // [256][256]
    const float* h_bias      = (const float*)d_in[4]; // [256]
    float*       out         = (float*)d_out;

    float* msg = (float*)d_ws;                 // [N][D]
    float* deg = msg + (size_t)N * D;          // [N]
    const size_t ws_needed = ((size_t)N * D + N) * sizeof(float);
    (void)ws_needed; (void)ws_size; (void)in_sizes; (void)n_in; (void)out_size;

    dim3 ggrid((N + 63) / 64, D / 64);

    // out = x @ loop_weight + bias
    gemm64<true><<<ggrid, 256, 0, stream>>>(x, loop_weight, nullptr, h_bias, out);

    for (int r = 0; r < R; ++r) {
        hipMemsetAsync(d_ws, 0, ws_needed, stream);
        const int* src = edges + (size_t)r * 2 * E;
        const int* dst = src + E;
        scatter_kernel<<<1024, 256, 0, stream>>>(x, src, dst, msg, deg);
        rdeg_kernel<<<(N + 255) / 256, 256, 0, stream>>>(deg);
        // out += (msg * rdeg) @ W_r
        gemm64<false><<<ggrid, 256, 0, stream>>>(msg, weight + (size_t)r * D * D,
                                                 deg, nullptr, out);
    }

    tanh_kernel<<<2048, 256, 0, stream>>>(out, (N * D) / 4);
}

// Round 2
// 1131.086 us; speedup vs baseline: 5.5031x; 5.5031x over previous
//
#include <hip/hip_runtime.h>
#include <cstdint>
#include <cstddef>

constexpr int N = 50000;   // nodes
constexpr int D = 256;     // D_IN == D_OUT
constexpr int E = 400000;  // edges per relation
constexpr int R = 4;       // relations

constexpr int SCAN_CHUNK = 1024;                       // elements per scan block
constexpr int NSCAN = (N + SCAN_CHUNK - 1) / SCAN_CHUNK;  // 49

// ---------------------------------------------------------------------------
// CSR build: count -> scan -> fill (counting sort of src by dst)
// ---------------------------------------------------------------------------
__global__ __launch_bounds__(256)
void count_kernel(const int* __restrict__ dst, int* __restrict__ cnt) {
    int i = blockIdx.x * blockDim.x + threadIdx.x;
    const int stride = gridDim.x * blockDim.x;
    for (; i < E; i += stride) atomicAdd(&cnt[dst[i]], 1);
}

// Per-block exclusive scan over 1024-element chunks; blocksums[b] = chunk total.
__global__ __launch_bounds__(256)
void scan_a_kernel(const int* __restrict__ cnt, int* __restrict__ excl,
                   int* __restrict__ blocksums) {
    __shared__ int s[256];
    const int t = threadIdx.x;
    const int base = blockIdx.x * SCAN_CHUNK;
    int v[4], sum = 0;
#pragma unroll
    for (int i = 0; i < 4; ++i) {
        const int idx = base + t * 4 + i;
        v[i] = (idx < N) ? cnt[idx] : 0;
        sum += v[i];
    }
    s[t] = sum;
    __syncthreads();
#pragma unroll
    for (int off = 1; off < 256; off <<= 1) {
        int val = (t >= off) ? s[t - off] : 0;
        __syncthreads();
        s[t] += val;
        __syncthreads();
    }
    int run = s[t] - sum;  // exclusive prefix of this thread's 4 items
#pragma unroll
    for (int i = 0; i < 4; ++i) {
        const int idx = base + t * 4 + i;
        if (idx < N) excl[idx] = run;
        run += v[i];
    }
    if (t == 0) blocksums[blockIdx.x] = s[255];
}

// Serial exclusive scan of the (49) block sums — single thread, trivial size.
__global__ void scan_b_kernel(int* __restrict__ blocksums) {
    if (threadIdx.x == 0 && blockIdx.x == 0) {
        int run = 0;
        for (int b = 0; b < NSCAN; ++b) {
            const int v = blocksums[b];
            blocksums[b] = run;
            run += v;
        }
    }
}

// Finalize: row_ptr (in place), pos copy for fill, rdeg = 1/max(deg,1).
__global__ __launch_bounds__(256)
void scan_c_kernel(int* __restrict__ row_ptr, const int* __restrict__ blocksums,
                   int* __restrict__ pos, const int* __restrict__ cnt,
                   float* __restrict__ rdeg) {
    const int i = blockIdx.x * blockDim.x + threadIdx.x;
    if (i >= N) return;
    const int rp = row_ptr[i] + blocksums[i >> 10];
    row_ptr[i] = rp;
    pos[i] = rp;
    rdeg[i] = 1.0f / fmaxf((float)cnt[i], 1.0f);
    if (i == 0) row_ptr[N] = E;  // every edge has an in-range dst
}

__global__ __launch_bounds__(256)
void fill_kernel(const int* __restrict__ src, const int* __restrict__ dst,
                 int* __restrict__ pos, int* __restrict__ src_sorted) {
    int i = blockIdx.x * blockDim.x + threadIdx.x;
    const int stride = gridDim.x * blockDim.x;
    for (; i < E; i += stride) {
        const int p = atomicAdd(&pos[dst[i]], 1);
        src_sorted[p] = src[i];
    }
}

// ---------------------------------------------------------------------------
// Pull-gather: one wave per destination node; 64 lanes x float4 = 256 floats.
// msg[n] = (sum over in-edges of x[src]) * rdeg[n]
// ---------------------------------------------------------------------------
__global__ __launch_bounds__(256)
void gather_kernel(const float* __restrict__ x, const int* __restrict__ row_ptr,
                   const int* __restrict__ src_sorted,
                   const float* __restrict__ rdeg, float* __restrict__ msg) {
    const int wave = (blockIdx.x * blockDim.x + threadIdx.x) >> 6;
    const int lane = threadIdx.x & 63;
    if (wave >= N) return;
    const int beg = row_ptr[wave];
    const int end = row_ptr[wave + 1];
    float4 acc = make_float4(0.f, 0.f, 0.f, 0.f);
    int j = beg;
    for (; j + 1 < end; j += 2) {  // 2-edge unroll for MLP
        const int s0 = src_sorted[j];
        const int s1 = src_sorted[j + 1];
        const float4 a =
            *reinterpret_cast<const float4*>(x + (size_t)s0 * D + lane * 4);
        const float4 b =
            *reinterpret_cast<const float4*>(x + (size_t)s1 * D + lane * 4);
        acc.x += a.x + b.x;
        acc.y += a.y + b.y;
        acc.z += a.z + b.z;
        acc.w += a.w + b.w;
    }
    if (j < end) {
        const int s0 = src_sorted[j];
        const float4 a =
            *reinterpret_cast<const float4*>(x + (size_t)s0 * D + lane * 4);
        acc.x += a.x;
        acc.y += a.y;
        acc.z += a.z;
        acc.w += a.w;
    }
    const float rs = rdeg[wave];
    float4 o;
    o.x = acc.x * rs;
    o.y = acc.y * rs;
    o.z = acc.z * rs;
    o.w = acc.w * rs;
    *reinterpret_cast<float4*>(msg + (size_t)wave * D + lane * 4) = o;
}

// ---------------------------------------------------------------------------
// Tiled fp32 GEMM: C[M,256] (+)= A @ W.  BM=BN=64, BK=16, 4x4 micro-tile.
// ---------------------------------------------------------------------------
template <bool INIT>
__global__ __launch_bounds__(256)
void gemm64(const float* __restrict__ A, const float* __restrict__ W,
            const float* __restrict__ bias, float* __restrict__ C) {
    __shared__ float As[16][65];
    __shared__ float Bs[16][65];

    const int t  = threadIdx.x;
    const int m0 = blockIdx.x * 64;
    const int n0 = blockIdx.y * 64;
    const int tx = t & 15;
    const int ty = t >> 4;

    const int ar   = t >> 2;
    const int ac   = (t & 3) * 4;
    const int arow = m0 + ar;
    const bool arow_ok = (arow < N);

    const int br = t >> 4;
    const int bc = (t & 15) * 4;

    float acc[4][4] = {};

    for (int k0 = 0; k0 < D; k0 += 16) {
        float4 av = make_float4(0.f, 0.f, 0.f, 0.f);
        if (arow_ok)
            av = *reinterpret_cast<const float4*>(A + (size_t)arow * D + k0 + ac);
        const float4 bv =
            *reinterpret_cast<const float4*>(W + (size_t)(k0 + br) * D + n0 + bc);

        __syncthreads();
        As[ac + 0][ar] = av.x;
        As[ac + 1][ar] = av.y;
        As[ac + 2][ar] = av.z;
        As[ac + 3][ar] = av.w;
        Bs[br][bc + 0] = bv.x;
        Bs[br][bc + 1] = bv.y;
        Bs[br][bc + 2] = bv.z;
        Bs[br][bc + 3] = bv.w;
        __syncthreads();

#pragma unroll
        for (int k = 0; k < 16; ++k) {
            float a[4], b[4];
#pragma unroll
            for (int i = 0; i < 4; ++i) a[i] = As[k][ty * 4 + i];
#pragma unroll
            for (int j = 0; j < 4; ++j) b[j] = Bs[k][tx * 4 + j];
#pragma unroll
            for (int i = 0; i < 4; ++i)
#pragma unroll
                for (int j = 0; j < 4; ++j) acc[i][j] += a[i] * b[j];
        }
    }

#pragma unroll
    for (int i = 0; i < 4; ++i) {
        const int row = m0 + ty * 4 + i;
        if (row >= N) continue;
#pragma unroll
        for (int j = 0; j < 4; ++j) {
            const int col = n0 + tx * 4 + j;
            const size_t idx = (size_t)row * D + col;
            if (INIT)
                C[idx] = acc[i][j] + bias[col];
            else
                C[idx] += acc[i][j];
        }
    }
}

__global__ void tanh_kernel(float* __restrict__ out, int n4) {
    int i = blockIdx.x * blockDim.x + threadIdx.x;
    const int stride = gridDim.x * blockDim.x;
    float4* p = reinterpret_cast<float4*>(out);
    for (; i < n4; i += stride) {
        float4 v = p[i];
        v.x = tanhf(v.x);
        v.y = tanhf(v.y);
        v.z = tanhf(v.z);
        v.w = tanhf(v.w);
        p[i] = v;
    }
}

extern "C" void kernel_launch(void* const* d_in, const int* in_sizes, int n_in,
                              void* d_out, int out_size, void* d_ws, size_t ws_size,
                              hipStream_t stream) {
    const float* x           = (const float*)d_in[0];
    const int*   edges       = (const int*)d_in[1];   // [4][2][400000] int32
    const float* weight      = (const float*)d_in[2]; // [4][256][256]
    const float* loop_weight = (const float*)d_in[3]; // [256][256]
    const float* h_bias      = (const float*)d_in[4]; // [256]
    float*       out         = (float*)d_out;
    (void)in_sizes; (void)n_in; (void)out_size; (void)ws_size;

    // workspace layout
    float* msg        = (float*)d_ws;                  // N*D floats
    int*   row_ptr    = (int*)(msg + (size_t)N * D);   // N+4
    int*   pos        = row_ptr + (N + 4);             // N
    int*   cnt        = pos + N;                       // N
    float* rdeg       = (float*)(cnt + N);             // N
    int*   src_sorted = (int*)(rdeg + N);              // E
    int*   blocksums  = src_sorted + E;                // 64

    dim3 ggrid((N + 63) / 64, D / 64);

    // out = x @ loop_weight + bias
    gemm64<true><<<ggrid, 256, 0, stream>>>(x, loop_weight, h_bias, out);

    const int gather_blocks = (N * 64 + 255) / 256;  // wave per node

    for (int r = 0; r < R; ++r) {
        const int* src = edges + (size_t)r * 2 * E;
        const int* dst = src + E;

        hipMemsetAsync(cnt, 0, N * sizeof(int), stream);
        count_kernel<<<512, 256, 0, stream>>>(dst, cnt);
        scan_a_kernel<<<NSCAN, 256, 0, stream>>>(cnt, row_ptr, blocksums);
        scan_b_kernel<<<1, 64, 0, stream>>>(blocksums);
        scan_c_kernel<<<(N + 255) / 256, 256, 0, stream>>>(row_ptr, blocksums,
                                                           pos, cnt, rdeg);
        fill_kernel<<<512, 256, 0, stream>>>(src, dst, pos, src_sorted);
        gather_kernel<<<gather_blocks, 256, 0, stream>>>(x, row_ptr, src_sorted,
                                                         rdeg, msg);
        gemm64<false><<<ggrid, 256, 0, stream>>>(msg, weight + (size_t)r * D * D,
                                                 nullptr, out);
    }

    tanh_kernel<<<2048, 256, 0, stream>>>(out, (N * D) / 4);
}

// Round 3
// 458.874 us; speedup vs baseline: 13.5646x; 2.4649x over previous
//
#include <hip/hip_runtime.h>
#include <cstdint>
#include <cstddef>

constexpr int N = 50000;   // nodes
constexpr int D = 256;     // D_IN == D_OUT
constexpr int E = 400000;  // edges per relation
constexpr int R = 4;       // relations
constexpr int N4 = N * R;  // 200000 (cnt/row_ptr space across relations)
constexpr int AROWS = 50048;  // 391 * 128, padded M

constexpr int SCAN_CHUNK = 1024;
constexpr int NSCAN4 = (N4 + SCAN_CHUNK - 1) / SCAN_CHUNK;  // 196

typedef _Float16 f16x8 __attribute__((ext_vector_type(8)));
typedef _Float16 f16x4 __attribute__((ext_vector_type(4)));
typedef float f32x4 __attribute__((ext_vector_type(4)));

// ---------------------------------------------------------------------------
// CSR build (all 4 relations batched): count -> scan(a,b,c) -> fill
// ---------------------------------------------------------------------------
__global__ __launch_bounds__(256)
void count4_kernel(const int* __restrict__ edges, int* __restrict__ cnt) {
    int i = blockIdx.x * blockDim.x + threadIdx.x;
    const int stride = gridDim.x * blockDim.x;
    for (; i < R * E; i += stride) {
        const int r = i / E;
        const int t = i - r * E;
        const int d = edges[(r * 2 + 1) * E + t];
        atomicAdd(&cnt[r * N + d], 1);
    }
}

__global__ __launch_bounds__(256)
void scan_a_kernel(const int* __restrict__ cnt, int* __restrict__ excl,
                   int* __restrict__ blocksums) {
    __shared__ int s[256];
    const int t = threadIdx.x;
    const int base = blockIdx.x * SCAN_CHUNK;
    int v[4], sum = 0;
#pragma unroll
    for (int i = 0; i < 4; ++i) {
        const int idx = base + t * 4 + i;
        v[i] = (idx < N4) ? cnt[idx] : 0;
        sum += v[i];
    }
    s[t] = sum;
    __syncthreads();
#pragma unroll
    for (int off = 1; off < 256; off <<= 1) {
        int val = (t >= off) ? s[t - off] : 0;
        __syncthreads();
        s[t] += val;
        __syncthreads();
    }
    int run = s[t] - sum;
#pragma unroll
    for (int i = 0; i < 4; ++i) {
        const int idx = base + t * 4 + i;
        if (idx < N4) excl[idx] = run;
        run += v[i];
    }
    if (t == 0) blocksums[blockIdx.x] = s[255];
}

// Parallel exclusive scan of <=256 block sums in one block.
__global__ __launch_bounds__(256)
void scan_b_kernel(int* __restrict__ bs, int nb) {
    __shared__ int s[256];
    const int t = threadIdx.x;
    const int v = (t < nb) ? bs[t] : 0;
    s[t] = v;
    __syncthreads();
#pragma unroll
    for (int off = 1; off < 256; off <<= 1) {
        int x = (t >= off) ? s[t - off] : 0;
        __syncthreads();
        s[t] += x;
        __syncthreads();
    }
    if (t < nb) bs[t] = s[t] - v;
}

__global__ __launch_bounds__(256)
void scan_c_kernel(int* __restrict__ row_ptr, const int* __restrict__ blocksums,
                   int* __restrict__ pos) {
    const int i = blockIdx.x * blockDim.x + threadIdx.x;
    if (i >= N4) return;
    const int rp = row_ptr[i] + blocksums[i >> 10];
    row_ptr[i] = rp;
    pos[i] = rp;
    if (i == 0) row_ptr[N4] = R * E;
}

__global__ __launch_bounds__(256)
void fill4_kernel(const int* __restrict__ edges, int* __restrict__ pos,
                  int* __restrict__ src_sorted) {
    int i = blockIdx.x * blockDim.x + threadIdx.x;
    const int stride = gridDim.x * blockDim.x;
    for (; i < R * E; i += stride) {
        const int r = i / E;
        const int t = i - r * E;
        const int s = edges[(r * 2 + 0) * E + t];
        const int d = edges[(r * 2 + 1) * E + t];
        const int p = atomicAdd(&pos[r * N + d], 1);
        src_sorted[p] = s;
    }
}

// ---------------------------------------------------------------------------
// x (fp32) -> fp16 plane (possibly embedded as columns of A with stride lda)
// ---------------------------------------------------------------------------
__global__ __launch_bounds__(256)
void convert_x_kernel(const float* __restrict__ x, _Float16* __restrict__ dst,
                      long lda) {
    const long i = (long)blockIdx.x * blockDim.x + threadIdx.x;  // per 8 elems
    if (i >= (long)N * (D / 8)) return;
    const long n = i >> 5;
    const int c8 = (int)(i & 31) << 3;
    const float4* s = reinterpret_cast<const float4*>(x + n * D + c8);
    const float4 a = s[0], b = s[1];
    f16x8 v;
    v[0] = (_Float16)a.x; v[1] = (_Float16)a.y;
    v[2] = (_Float16)a.z; v[3] = (_Float16)a.w;
    v[4] = (_Float16)b.x; v[5] = (_Float16)b.y;
    v[6] = (_Float16)b.z; v[7] = (_Float16)b.w;
    *reinterpret_cast<f16x8*>(dst + n * lda + c8) = v;
}

// Stacked transposed weights: WT[c][k], k in [0,1280): k<1024 -> W_{k/256},
// else loop_weight. fp16.
__global__ __launch_bounds__(256)
void wt_build_kernel(const float* __restrict__ w, const float* __restrict__ lw,
                     _Float16* __restrict__ wt) {
    const int i = blockIdx.x * blockDim.x + threadIdx.x;  // c*1280 + k
    if (i >= 256 * 1280) return;
    const int c = i / 1280;
    const int k = i - c * 1280;
    const float v = (k < 1024) ? w[((k >> 8) << 16) + ((k & 255) << 8) + c]
                               : lw[((k - 1024) << 8) + c];
    wt[i] = (_Float16)v;
}

// ---------------------------------------------------------------------------
// Gather: wave per node; for each relation in [r0,r1): sum fp16 x-rows of
// in-neighbors (fp32 acc), normalize by 1/max(deg,1), write fp16 into A.
// ---------------------------------------------------------------------------
__global__ __launch_bounds__(256)
void gather_kernel(const _Float16* __restrict__ xh, long xlda,
                   const int* __restrict__ row_ptr, const int* __restrict__ cnt,
                   const int* __restrict__ src_sorted,
                   _Float16* __restrict__ Aout, long lda, int relstride,
                   int r0, int r1) {
    const int wid = (blockIdx.x * blockDim.x + threadIdx.x) >> 6;
    const int lane = threadIdx.x & 63;
    if (wid >= N) return;
    for (int r = r0; r < r1; ++r) {
        const int base = r * N + wid;
        const int beg = row_ptr[base];
        const int end = row_ptr[base + 1];
        float4 acc = make_float4(0.f, 0.f, 0.f, 0.f);
        int j = beg;
        for (; j + 1 < end; j += 2) {
            const int s0 = src_sorted[j];
            const int s1 = src_sorted[j + 1];
            const f16x4 a =
                *reinterpret_cast<const f16x4*>(xh + (long)s0 * xlda + lane * 4);
            const f16x4 b =
                *reinterpret_cast<const f16x4*>(xh + (long)s1 * xlda + lane * 4);
            acc.x += (float)a[0] + (float)b[0];
            acc.y += (float)a[1] + (float)b[1];
            acc.z += (float)a[2] + (float)b[2];
            acc.w += (float)a[3] + (float)b[3];
        }
        if (j < end) {
            const int s0 = src_sorted[j];
            const f16x4 a =
                *reinterpret_cast<const f16x4*>(xh + (long)s0 * xlda + lane * 4);
            acc.x += (float)a[0];
            acc.y += (float)a[1];
            acc.z += (float)a[2];
            acc.w += (float)a[3];
        }
        const float rs = 1.0f / fmaxf((float)cnt[base], 1.0f);
        f16x4 o;
        o[0] = (_Float16)(acc.x * rs);
        o[1] = (_Float16)(acc.y * rs);
        o[2] = (_Float16)(acc.z * rs);
        o[3] = (_Float16)(acc.w * rs);
        *reinterpret_cast<f16x4*>(Aout + (long)wid * lda +
                                  (long)(r - r0) * relstride + lane * 4) = o;
    }
}

// ---------------------------------------------------------------------------
// fp16 MFMA GEMM: C[M,256] = A[M,K] @ WT^T (+bias) (tanh), fp32 accum.
// 128x128 tile, 4 waves, BK=32, k-subtiled LDS [4][128][8] (conflict-free).
// flags: bit0 = init (add bias, overwrite C), else accumulate into C.
//        bit1 = tanh epilogue.
// ---------------------------------------------------------------------------
__global__ __launch_bounds__(256)
void gemm_f16_kernel(const _Float16* __restrict__ A, long lda,
                     const _Float16* __restrict__ WT, long ldwt, int K,
                     const float* __restrict__ bias, float* __restrict__ C,
                     int Mreal, int flags) {
    __shared__ _Float16 As[4][128][8];
    __shared__ _Float16 Bs[4][128][8];

    const int t = threadIdx.x;
    const int lane = t & 63;
    const int w = t >> 6;
    const int wr = w >> 1;
    const int wc = w & 1;
    const long m0 = (long)blockIdx.x * 128;
    const int n0 = blockIdx.y * 128;

    // staging map: thread covers 16 fp16 (32B): row t>>1, cols (t&1)*16..+16
    const int srow = t >> 1;
    const int skg = (t & 1) * 2;  // k-subtile group of first 8 elems
    const _Float16* Ag = A + (m0 + srow) * lda + (t & 1) * 16;
    const _Float16* Bg = WT + (long)(n0 + srow) * ldwt + (t & 1) * 16;

    f32x4 acc[4][4];
#pragma unroll
    for (int i = 0; i < 4; ++i)
#pragma unroll
        for (int j = 0; j < 4; ++j) acc[i][j] = (f32x4){0.f, 0.f, 0.f, 0.f};

    const int kg = lane >> 4;   // k-subtile for frag reads
    const int rr = lane & 15;

    for (int k0 = 0; k0 < K; k0 += 32) {
        const uint4 av0 = *reinterpret_cast<const uint4*>(Ag + k0);
        const uint4 av1 = *reinterpret_cast<const uint4*>(Ag + k0 + 8);
        const uint4 bv0 = *reinterpret_cast<const uint4*>(Bg + k0);
        const uint4 bv1 = *reinterpret_cast<const uint4*>(Bg + k0 + 8);
        __syncthreads();  // previous iteration's frag reads done
        *reinterpret_cast<uint4*>(&As[skg + 0][srow][0]) = av0;
        *reinterpret_cast<uint4*>(&As[skg + 1][srow][0]) = av1;
        *reinterpret_cast<uint4*>(&Bs[skg + 0][srow][0]) = bv0;
        *reinterpret_cast<uint4*>(&Bs[skg + 1][srow][0]) = bv1;
        __syncthreads();

        f16x8 af[4], bf[4];
#pragma unroll
        for (int f = 0; f < 4; ++f) {
            af[f] = *reinterpret_cast<const f16x8*>(&As[kg][wr * 64 + f * 16 + rr][0]);
            bf[f] = *reinterpret_cast<const f16x8*>(&Bs[kg][wc * 64 + f * 16 + rr][0]);
        }
#pragma unroll
        for (int i = 0; i < 4; ++i)
#pragma unroll
            for (int j = 0; j < 4; ++j)
                acc[i][j] = __builtin_amdgcn_mfma_f32_16x16x32_f16(
                    af[i], bf[j], acc[i][j], 0, 0, 0);
    }

    // epilogue: C/D map col=lane&15, row=(lane>>4)*4+reg
    const int crow0 = (lane >> 4) * 4;
    const int ccol = lane & 15;
#pragma unroll
    for (int i = 0; i < 4; ++i) {
        const long row = m0 + wr * 64 + i * 16 + crow0;
#pragma unroll
        for (int j = 0; j < 4; ++j) {
            const int col = n0 + wc * 64 + j * 16 + ccol;
            const float b = (flags & 1) ? bias[col] : 0.f;
#pragma unroll
            for (int q = 0; q < 4; ++q) {
                const long rgl = row + q;
                if (rgl < Mreal) {
                    float v = acc[i][j][q] + b;
                    float* cp = C + rgl * 256 + col;
                    if (!(flags & 1)) v += *cp;
                    if (flags & 2) v = tanhf(v);
                    *cp = v;
                }
            }
        }
    }
}

__global__ void tanh_kernel(float* __restrict__ out, int n4) {
    int i = blockIdx.x * blockDim.x + threadIdx.x;
    const int stride = gridDim.x * blockDim.x;
    float4* p = reinterpret_cast<float4*>(out);
    for (; i < n4; i += stride) {
        float4 v = p[i];
        v.x = tanhf(v.x);
        v.y = tanhf(v.y);
        v.z = tanhf(v.z);
        v.w = tanhf(v.w);
        p[i] = v;
    }
}

// ---------------------------------------------------------------------------
extern "C" void kernel_launch(void* const* d_in, const int* in_sizes, int n_in,
                              void* d_out, int out_size, void* d_ws, size_t ws_size,
                              hipStream_t stream) {
    const float* x           = (const float*)d_in[0];
    const int*   edges       = (const int*)d_in[1];   // [4][2][400000] int32
    const float* weight      = (const float*)d_in[2]; // [4][256][256]
    const float* loop_weight = (const float*)d_in[3]; // [256][256]
    const float* h_bias      = (const float*)d_in[4]; // [256]
    float*       out         = (float*)d_out;
    (void)in_sizes; (void)n_in; (void)out_size;

    // ---- workspace carve-out helpers
    size_t off = 0;
    auto carve = [&](size_t bytes) -> void* {
        void* p = (char*)d_ws + off;
        off = (off + bytes + 15) & ~(size_t)15;
        return p;
    };

    const size_t a_main_bytes = (size_t)AROWS * 1280 * sizeof(_Float16);
    const size_t a_seq_bytes  = (size_t)AROWS * 256 * sizeof(_Float16);
    const size_t wt_bytes     = (size_t)256 * 1280 * sizeof(_Float16);
    const size_t srt_bytes    = (size_t)R * E * sizeof(int);
    const size_t cnt_bytes    = (size_t)N4 * sizeof(int);
    const size_t rp_bytes     = (size_t)(N4 + 1) * sizeof(int);
    const size_t pos_bytes    = (size_t)N4 * sizeof(int);
    const size_t bs_bytes     = 1024;

    const size_t need_main = ((a_main_bytes + 15) & ~15UL) + ((wt_bytes + 15) & ~15UL) +
                             ((srt_bytes + 15) & ~15UL) + ((cnt_bytes + 15) & ~15UL) +
                             ((rp_bytes + 15) & ~15UL) + ((pos_bytes + 15) & ~15UL) +
                             bs_bytes;
    const bool main_path = (ws_size >= need_main);

    _Float16* Abuf = (_Float16*)carve(main_path ? a_main_bytes : a_seq_bytes);
    _Float16* xh   = main_path ? (Abuf + 1024)  // columns 1024..1280 of A
                               : (_Float16*)carve(a_seq_bytes);
    const long xlda = main_path ? 1280 : 256;
    _Float16* WT   = (_Float16*)carve(wt_bytes);
    int* src_sorted = (int*)carve(srt_bytes);
    int* cnt        = (int*)carve(cnt_bytes);
    int* row_ptr    = (int*)carve(rp_bytes);
    int* pos        = (int*)carve(pos_bytes);
    int* blocksums  = (int*)carve(bs_bytes);

    // ---- CSR build (batched over all 4 relations)
    hipMemsetAsync(cnt, 0, cnt_bytes, stream);
    wt_build_kernel<<<(256 * 1280 + 255) / 256, 256, 0, stream>>>(weight, loop_weight, WT);
    count4_kernel<<<2048, 256, 0, stream>>>(edges, cnt);
    scan_a_kernel<<<NSCAN4, 256, 0, stream>>>(cnt, row_ptr, blocksums);
    scan_b_kernel<<<1, 256, 0, stream>>>(blocksums, NSCAN4);
    scan_c_kernel<<<(N4 + 255) / 256, 256, 0, stream>>>(row_ptr, blocksums, pos);
    fill4_kernel<<<2048, 256, 0, stream>>>(edges, pos, src_sorted);

    // ---- x -> fp16
    const int cvt_threads = N * (D / 8);
    convert_x_kernel<<<(cvt_threads + 255) / 256, 256, 0, stream>>>(x, xh, xlda);

    const int gather_blocks = (N * 64 + 255) / 256;
    const dim3 ggrid((AROWS) / 128, 2);

    if (main_path) {
        // gather all relations into A columns [0,1024)
        gather_kernel<<<gather_blocks, 256, 0, stream>>>(
            xh, xlda, row_ptr, cnt, src_sorted, Abuf, 1280, 256, 0, R);
        // single fused GEMM: out = tanh(A @ Wcat + bias)
        gemm_f16_kernel<<<ggrid, 256, 0, stream>>>(
            Abuf, 1280, WT, 1280, 1280, h_bias, out, N, /*init|tanh*/ 3);
    } else {
        // sequential fallback: self-loop first (init+bias), then 4 relations
        gemm_f16_kernel<<<ggrid, 256, 0, stream>>>(
            xh, 256, WT + 1024, 1280, 256, h_bias, out, N, /*init*/ 1);
        for (int r = 0; r < R; ++r) {
            gather_kernel<<<gather_blocks, 256, 0, stream>>>(
                xh, 256, row_ptr, cnt, src_sorted, Abuf, 256, 0, r, r + 1);
            gemm_f16_kernel<<<ggrid, 256, 0, stream>>>(
                Abuf, 256, WT + r * 256, 1280, 256, nullptr, out, N, /*acc*/ 0);
        }
        tanh_kernel<<<2048, 256, 0, stream>>>(out, (N * D) / 4);
    }
}

// Round 4
// 335.863 us; speedup vs baseline: 18.5327x; 1.3663x over previous
//
#include <hip/hip_runtime.h>
#include <cstdint>
#include <cstddef>

constexpr int N = 50000;      // nodes
constexpr int D = 256;        // D_IN == D_OUT
constexpr int E = 400000;     // edges per relation
constexpr int R = 4;          // relations
constexpr int N4 = N * R;     // cnt/row_ptr space across relations
constexpr int AROWS = 50048;  // 391 * 128, padded M
constexpr int KCAT = 1280;    // 4 relation planes + loop plane

constexpr int SCAN_CHUNK = 1024;
constexpr int NSCAN4 = (N4 + SCAN_CHUNK - 1) / SCAN_CHUNK;  // 196

typedef _Float16 f16x8 __attribute__((ext_vector_type(8)));
typedef _Float16 f16x4 __attribute__((ext_vector_type(4)));
typedef float f32x4 __attribute__((ext_vector_type(4)));

// ---------------------------------------------------------------------------
// Stacked transposed weights: WT[n][k], n in [0,1280):
//   n < 1024 -> W_{n/256}[k][n%256], else loop_weight[k][n-1024]. fp16.
// ---------------------------------------------------------------------------
__global__ __launch_bounds__(256)
void wt_build_kernel(const float* __restrict__ w, const float* __restrict__ lw,
                     _Float16* __restrict__ wt) {
    const int i = blockIdx.x * blockDim.x + threadIdx.x;  // n*256 + k
    if (i >= KCAT * 256) return;
    const int n = i >> 8;
    const int k = i & 255;
    const float v = (n < 1024) ? w[((n >> 8) << 16) + (k << 8) + (n & 255)]
                               : lw[(k << 8) + (n - 1024)];
    wt[i] = (_Float16)v;
}

// ---------------------------------------------------------------------------
// CSR build, single atomic pass:
//   rank[i] = old count (per dst)  ->  scan(cnt) -> row_ptr
//   fill: src16[row_ptr[dst] + rank[i]] = src   (no atomics)
// ---------------------------------------------------------------------------
__global__ __launch_bounds__(256)
void rank_kernel(const int* __restrict__ edges, int* __restrict__ cnt,
                 ushort* __restrict__ rank16) {
    const int r = blockIdx.y;
    const int* dst = edges + (r * 2 + 1) * E;
    int i = blockIdx.x * blockDim.x + threadIdx.x;
    const int stride = gridDim.x * blockDim.x;
    for (; i < E; i += stride)
        rank16[r * E + i] = (ushort)atomicAdd(&cnt[r * N + dst[i]], 1);
}

__global__ __launch_bounds__(256)
void scan_a_kernel(const int* __restrict__ cnt, int* __restrict__ excl,
                   int* __restrict__ blocksums) {
    __shared__ int s[256];
    const int t = threadIdx.x;
    const int base = blockIdx.x * SCAN_CHUNK;
    int v[4], sum = 0;
#pragma unroll
    for (int i = 0; i < 4; ++i) {
        const int idx = base + t * 4 + i;
        v[i] = (idx < N4) ? cnt[idx] : 0;
        sum += v[i];
    }
    s[t] = sum;
    __syncthreads();
#pragma unroll
    for (int off = 1; off < 256; off <<= 1) {
        int val = (t >= off) ? s[t - off] : 0;
        __syncthreads();
        s[t] += val;
        __syncthreads();
    }
    int run = s[t] - sum;
#pragma unroll
    for (int i = 0; i < 4; ++i) {
        const int idx = base + t * 4 + i;
        if (idx < N4) excl[idx] = run;
        run += v[i];
    }
    if (t == 0) blocksums[blockIdx.x] = s[255];
}

__global__ __launch_bounds__(256)
void scan_b_kernel(int* __restrict__ bs, int nb) {
    __shared__ int s[256];
    const int t = threadIdx.x;
    const int v = (t < nb) ? bs[t] : 0;
    s[t] = v;
    __syncthreads();
#pragma unroll
    for (int off = 1; off < 256; off <<= 1) {
        int x = (t >= off) ? s[t - off] : 0;
        __syncthreads();
        s[t] += x;
        __syncthreads();
    }
    if (t < nb) bs[t] = s[t] - v;
}

__global__ __launch_bounds__(256)
void scan_c_kernel(int* __restrict__ row_ptr, const int* __restrict__ blocksums) {
    const int i = blockIdx.x * blockDim.x + threadIdx.x;
    if (i >= N4) return;
    row_ptr[i] += blocksums[i >> 10];
    if (i == 0) row_ptr[N4] = R * E;
}

__global__ __launch_bounds__(256)
void fill_kernel(const int* __restrict__ edges, const int* __restrict__ row_ptr,
                 const ushort* __restrict__ rank16, ushort* __restrict__ src16) {
    const int r = blockIdx.y;
    const int* srcp = edges + r * 2 * E;
    const int* dstp = srcp + E;
    int i = blockIdx.x * blockDim.x + threadIdx.x;
    const int stride = gridDim.x * blockDim.x;
    for (; i < E; i += stride) {
        const int p = row_ptr[r * N + dstp[i]] + (int)rank16[r * E + i];
        src16[p] = (ushort)srcp[i];
    }
}

// ---------------------------------------------------------------------------
// y[M,1280] (fp16) = x[M,256] (fp32, inline-converted) @ WT[1280,256]^T
// 128x128 tile, 4 waves, BK=32, k-subtiled LDS [4][128][8] (conflict-free).
// ---------------------------------------------------------------------------
__global__ __launch_bounds__(256)
void gemm_xw_kernel(const float* __restrict__ x, const _Float16* __restrict__ WT,
                    _Float16* __restrict__ y) {
    __shared__ _Float16 As[4][128][8];
    __shared__ _Float16 Bs[4][128][8];

    const int t = threadIdx.x;
    const int lane = t & 63;
    const int w = t >> 6;
    const int wr = w >> 1;
    const int wc = w & 1;
    const long m0 = (long)blockIdx.x * 128;
    const int n0 = blockIdx.y * 128;

    const int srow = t >> 1;          // 0..127
    const int half = t & 1;           // which 16-wide k half
    const int skg = half * 2;         // first k-subtile this thread writes
    const long arow = m0 + srow;
    const bool arow_ok = (arow < N);
    const float* Ag = x + arow * D + half * 16;
    const _Float16* Bg = WT + (long)(n0 + srow) * 256 + half * 16;

    f32x4 acc[4][4];
#pragma unroll
    for (int i = 0; i < 4; ++i)
#pragma unroll
        for (int j = 0; j < 4; ++j) acc[i][j] = (f32x4){0.f, 0.f, 0.f, 0.f};

    const int kg = lane >> 4;
    const int rr = lane & 15;

    for (int k0 = 0; k0 < D; k0 += 32) {
        float4 a0 = make_float4(0, 0, 0, 0), a1 = a0, a2 = a0, a3 = a0;
        if (arow_ok) {
            a0 = *reinterpret_cast<const float4*>(Ag + k0);
            a1 = *reinterpret_cast<const float4*>(Ag + k0 + 4);
            a2 = *reinterpret_cast<const float4*>(Ag + k0 + 8);
            a3 = *reinterpret_cast<const float4*>(Ag + k0 + 12);
        }
        const uint4 bv0 = *reinterpret_cast<const uint4*>(Bg + k0);
        const uint4 bv1 = *reinterpret_cast<const uint4*>(Bg + k0 + 8);

        f16x8 ah0, ah1;
        ah0[0] = (_Float16)a0.x; ah0[1] = (_Float16)a0.y;
        ah0[2] = (_Float16)a0.z; ah0[3] = (_Float16)a0.w;
        ah0[4] = (_Float16)a1.x; ah0[5] = (_Float16)a1.y;
        ah0[6] = (_Float16)a1.z; ah0[7] = (_Float16)a1.w;
        ah1[0] = (_Float16)a2.x; ah1[1] = (_Float16)a2.y;
        ah1[2] = (_Float16)a2.z; ah1[3] = (_Float16)a2.w;
        ah1[4] = (_Float16)a3.x; ah1[5] = (_Float16)a3.y;
        ah1[6] = (_Float16)a3.z; ah1[7] = (_Float16)a3.w;

        __syncthreads();  // previous iteration's frag reads done
        *reinterpret_cast<f16x8*>(&As[skg + 0][srow][0]) = ah0;
        *reinterpret_cast<f16x8*>(&As[skg + 1][srow][0]) = ah1;
        *reinterpret_cast<uint4*>(&Bs[skg + 0][srow][0]) = bv0;
        *reinterpret_cast<uint4*>(&Bs[skg + 1][srow][0]) = bv1;
        __syncthreads();

        f16x8 af[4], bf[4];
#pragma unroll
        for (int f = 0; f < 4; ++f) {
            af[f] = *reinterpret_cast<const f16x8*>(&As[kg][wr * 64 + f * 16 + rr][0]);
            bf[f] = *reinterpret_cast<const f16x8*>(&Bs[kg][wc * 64 + f * 16 + rr][0]);
        }
#pragma unroll
        for (int i = 0; i < 4; ++i)
#pragma unroll
            for (int j = 0; j < 4; ++j)
                acc[i][j] = __builtin_amdgcn_mfma_f32_16x16x32_f16(
                    af[i], bf[j], acc[i][j], 0, 0, 0);
    }

    // epilogue: C/D map col=lane&15, row=(lane>>4)*4+reg
    const int crow0 = (lane >> 4) * 4;
    const int ccol = lane & 15;
#pragma unroll
    for (int i = 0; i < 4; ++i) {
        const long row = m0 + wr * 64 + i * 16 + crow0;
#pragma unroll
        for (int j = 0; j < 4; ++j) {
            const int col = n0 + wc * 64 + j * 16 + ccol;
#pragma unroll
            for (int q = 0; q < 4; ++q) {
                const long rgl = row + q;
                if (rgl < N) y[rgl * KCAT + col] = (_Float16)acc[i][j][q];
            }
        }
    }
}

// ---------------------------------------------------------------------------
// Final fused pull: wave per node n.
//   out[n] = tanh( sum_r (1/max(deg_r,1)) * sum_{e in-edges} y_r[src]
//                  + y_loop[n] + bias )
// ---------------------------------------------------------------------------
__global__ __launch_bounds__(256)
void final_kernel(const _Float16* __restrict__ y, const int* __restrict__ row_ptr,
                  const ushort* __restrict__ src16, const float* __restrict__ bias,
                  float* __restrict__ out) {
    const int n = (blockIdx.x * blockDim.x + threadIdx.x) >> 6;
    const int lane = threadIdx.x & 63;
    if (n >= N) return;

    const float4 bv = *reinterpret_cast<const float4*>(bias + lane * 4);
    const f16x4 lv =
        *reinterpret_cast<const f16x4*>(y + (long)n * KCAT + 1024 + lane * 4);
    float4 acc;
    acc.x = bv.x + (float)lv[0];
    acc.y = bv.y + (float)lv[1];
    acc.z = bv.z + (float)lv[2];
    acc.w = bv.w + (float)lv[3];

#pragma unroll
    for (int r = 0; r < R; ++r) {
        const int base = r * N + n;
        const int beg = row_ptr[base];
        const int end = row_ptr[base + 1];
        float4 racc = make_float4(0.f, 0.f, 0.f, 0.f);
        const long plane = r * 256 + lane * 4;
        int j = beg;
        for (; j + 3 < end; j += 4) {
            const int s0 = src16[j], s1 = src16[j + 1];
            const int s2 = src16[j + 2], s3 = src16[j + 3];
            const f16x4 v0 = *reinterpret_cast<const f16x4*>(y + (long)s0 * KCAT + plane);
            const f16x4 v1 = *reinterpret_cast<const f16x4*>(y + (long)s1 * KCAT + plane);
            const f16x4 v2 = *reinterpret_cast<const f16x4*>(y + (long)s2 * KCAT + plane);
            const f16x4 v3 = *reinterpret_cast<const f16x4*>(y + (long)s3 * KCAT + plane);
            racc.x += (float)v0[0] + (float)v1[0] + (float)v2[0] + (float)v3[0];
            racc.y += (float)v0[1] + (float)v1[1] + (float)v2[1] + (float)v3[1];
            racc.z += (float)v0[2] + (float)v1[2] + (float)v2[2] + (float)v3[2];
            racc.w += (float)v0[3] + (float)v1[3] + (float)v2[3] + (float)v3[3];
        }
        for (; j < end; ++j) {
            const int s0 = src16[j];
            const f16x4 v0 = *reinterpret_cast<const f16x4*>(y + (long)s0 * KCAT + plane);
            racc.x += (float)v0[0];
            racc.y += (float)v0[1];
            racc.z += (float)v0[2];
            racc.w += (float)v0[3];
        }
        const float rs = 1.0f / fmaxf((float)(end - beg), 1.0f);
        acc.x += racc.x * rs;
        acc.y += racc.y * rs;
        acc.z += racc.z * rs;
        acc.w += racc.w * rs;
    }

    float4 o;
    o.x = tanhf(acc.x);
    o.y = tanhf(acc.y);
    o.z = tanhf(acc.z);
    o.w = tanhf(acc.w);
    *reinterpret_cast<float4*>(out + (long)n * D + lane * 4) = o;
}

// ---------------------------------------------------------------------------
extern "C" void kernel_launch(void* const* d_in, const int* in_sizes, int n_in,
                              void* d_out, int out_size, void* d_ws, size_t ws_size,
                              hipStream_t stream) {
    const float* x           = (const float*)d_in[0];
    const int*   edges       = (const int*)d_in[1];   // [4][2][400000] int32
    const float* weight      = (const float*)d_in[2]; // [4][256][256]
    const float* loop_weight = (const float*)d_in[3]; // [256][256]
    const float* h_bias      = (const float*)d_in[4]; // [256]
    float*       out         = (float*)d_out;
    (void)in_sizes; (void)n_in; (void)out_size; (void)ws_size;

    size_t off = 0;
    auto carve = [&](size_t bytes) -> void* {
        void* p = (char*)d_ws + off;
        off = (off + bytes + 255) & ~(size_t)255;
        return p;
    };

    _Float16* y        = (_Float16*)carve((size_t)AROWS * KCAT * sizeof(_Float16));
    _Float16* WT       = (_Float16*)carve((size_t)KCAT * 256 * sizeof(_Float16));
    ushort*   src16    = (ushort*)carve((size_t)R * E * sizeof(ushort));
    ushort*   rank16   = (ushort*)carve((size_t)R * E * sizeof(ushort));
    int*      cnt      = (int*)carve((size_t)N4 * sizeof(int));
    int*      row_ptr  = (int*)carve((size_t)(N4 + 1) * sizeof(int));
    int*      blocksums = (int*)carve(1024);

    // CSR build (single atomic pass)
    hipMemsetAsync(cnt, 0, (size_t)N4 * sizeof(int), stream);
    wt_build_kernel<<<(KCAT * 256 + 255) / 256, 256, 0, stream>>>(weight, loop_weight, WT);
    rank_kernel<<<dim3(512, R), 256, 0, stream>>>(edges, cnt, rank16);
    scan_a_kernel<<<NSCAN4, 256, 0, stream>>>(cnt, row_ptr, blocksums);
    scan_b_kernel<<<1, 256, 0, stream>>>(blocksums, NSCAN4);
    scan_c_kernel<<<(N4 + 255) / 256, 256, 0, stream>>>(row_ptr, blocksums);
    fill_kernel<<<dim3(512, R), 256, 0, stream>>>(edges, row_ptr, rank16, src16);

    // y = x @ Wcat   (fp16 out, fp32 accum)
    gemm_xw_kernel<<<dim3(AROWS / 128, KCAT / 128), 256, 0, stream>>>(x, WT, y);

    // out = tanh(sum_r deg^-1 * gather(y_r) + y_loop + bias)
    final_kernel<<<(N * 64) / 256, 256, 0, stream>>>(y, row_ptr, src16, h_bias, out);
}